// Round 10
// baseline (191.358 us; speedup 1.0000x reference)
//
#include <hip/hip_runtime.h>

#define B_    16
#define N_    4096
#define S_    1024
#define K_    32
#define DIN_  64
#define DINC_ 67
#define DOUT_ 64
#define ROWS_ (B_ * N_)
#define NCH   128            // 64 proj + 64 xp output columns
#define NTILE 28             // nonzero weight tiles (s0:8, s1:8, s2:4, s3:4, s4:4)
#define NFRAG (NTILE * 64)   // 1792 16B-chunks = 28 KB
#define ASTR  168            // LDS act row stride in ushorts (336 B = 21*16)
#define WLDSB (NTILE * 64 * 16)        // 28672 B weight frags
#define ALDSB (64 * ASTR * 2)          // 21504 B activations
#define NBLK  512            // fused grid: 64 blocks per slab x 8 slabs
// K-REORDER: k' = 0..63 -> x (w2), k' = 64..130 -> xc (w1), 131..159 zero.
// cmb row: 128 bf16 = [proj x64 | xp x64] = 256 B

typedef float f32x4 __attribute__((ext_vector_type(4)));
typedef short s16x8 __attribute__((ext_vector_type(8)));

static __device__ __forceinline__ unsigned short f2bf(float f) {
    unsigned int u = __float_as_uint(f);
    u = (u + 0x7fffu + ((u >> 16) & 1u)) >> 16;   // RNE
    return (unsigned short)u;
}
static __device__ __forceinline__ float bf2f(unsigned short h) {
    return __uint_as_float((unsigned int)h << 16);
}
static __device__ __forceinline__ unsigned int pack2(float a, float b) {
    return (unsigned int)f2bf(a) | ((unsigned int)f2bf(b) << 16);
}

// ---------------------------------------------------------------------------
// Prep: build the 28 nonzero MFMA weight-fragment tiles (unchanged math) AND
// zero the 8 per-slab barrier counters (ws is re-poisoned 0xAA every launch).
// ---------------------------------------------------------------------------
__global__ __launch_bounds__(256) void prep_kernel(
    const float* __restrict__ w1, const float* __restrict__ w2,
    const int* __restrict__ use_x_p, uint4* __restrict__ wf,
    unsigned int* __restrict__ bar)
{
    const int id = blockIdx.x * 256 + threadIdx.x;
    if (id >= NFRAG) {
        const int z = id - NFRAG;
        if (z < 128) bar[z] = 0u;      // 8 slots x 16 uints (64 B apart)
        return;
    }
    const int tile = id >> 6;
    const int l    = id & 63;
    const int s    = (tile < 16) ? (tile >> 3) : (2 + ((tile - 16) >> 2));
    const int nt   = (tile < 16) ? (tile & 7)  : ((tile - 16) & 3);
    const int q    = l >> 4, m = l & 15;
    const int c    = nt * 16 + m;
    const int ux   = use_x_p[0];

    unsigned int w[4];
#pragma unroll
    for (int p = 0; p < 4; ++p) {
        unsigned short h[2];
#pragma unroll
        for (int e = 0; e < 2; ++e) {
            const int k = s * 32 + q * 8 + p * 2 + e;   // k'
            float v = 0.f;
            if (c < 64) {
                if (k < 64)         v = ux ? w2[c * DIN_ + k] : 0.f;
                else if (k < 131)   v = w1[c * DINC_ + (k - 64)];
            } else {
                if (k < 64)         v = w2[(c - 64) * DIN_ + k];
            }
            h[e] = f2bf(v);
        }
        w[p] = (unsigned int)h[0] | ((unsigned int)h[1] << 16);
    }
    wf[id] = make_uint4(w[0], w[1], w[2], w[3]);
}

// ---------------------------------------------------------------------------
// FUSED kernel: proj (2 x 64-row MFMA tiles per block) then gather (16 groups
// per block), with a per-slab producer/consumer barrier in between.
// 512 blocks: slab g = blockIdx&7 (matches the XCD round-robin heuristic for
// L2 locality, but correctness uses device-scope fence+atomics only).
// Residency proof: LDS 50176 B -> >=2 blocks/CU worst case; VGPR<=256 via
// __launch_bounds__(256,2); 512 <= 2*256 -> all blocks resident, no deadlock.
// ---------------------------------------------------------------------------
__global__ __launch_bounds__(256, 2) void fused_kernel(
    const float* __restrict__ x, const float* __restrict__ xcm,
    const uint4* __restrict__ wf, const float* __restrict__ bias,
    const int* __restrict__ indexes, const int* __restrict__ use_x_p,
    unsigned short* __restrict__ cmb, unsigned int* __restrict__ bar,
    float* __restrict__ out)
{
    __shared__ char smem[WLDSB + ALDSB];      // 50176 B
    uint4* ldsb          = (uint4*)smem;
    unsigned short* lact = (unsigned short*)(smem + WLDSB);
    unsigned int*  ldsd  = (unsigned int*)lact;

    const int t  = threadIdx.x;
    const int g  = blockIdx.x & 7;            // slab
    const int bs = blockIdx.x >> 3;           // slot within slab, 0..63
    const int ux = use_x_p[0];

    // ---- wf: direct global->LDS DMA once per block (reused by both tiles) --
#pragma unroll
    for (int j = 0; j < 7; ++j) {
        const int idx = j * 256 + t;
        __builtin_amdgcn_global_load_lds(
            (const __attribute__((address_space(1))) void*)(wf + idx),
            (__attribute__((address_space(3))) void*)(ldsb + idx), 16, 0, 0);
    }

    const int l = t & 63;
    const int w = __builtin_amdgcn_readfirstlane(t >> 6);
    const int q = l >> 4, m = l & 15;

    // ======================= proj phase: 2 tiles ===========================
#pragma unroll 1
    for (int it = 0; it < 2; ++it) {
        const int row0 = g * (ROWS_ / 8) + (bs * 2 + it) * 64;

        // ---- x: 1024 float4 per tile, 4 per thread ----
        {
            const float4* sx4 = (const float4*)(x + (size_t)row0 * DIN_);
#pragma unroll
            for (int j = 0; j < 4; ++j) {
                const int idx = j * 256 + t;
                const float4 v = sx4[idx];
                const int row = idx >> 4, f4 = idx & 15;
                *(uint2*)(ldsd + row * 84 + f4 * 2) =
                    make_uint2(pack2(v.x, v.y), pack2(v.z, v.w));
            }
        }
        // ---- xc: flat stream of 4288 floats = 1072 float4 ----
        {
            const float4* sc4 = (const float4*)(xcm + (size_t)row0 * DINC_);
#pragma unroll
            for (int j = 0; j < 5; ++j) {
                const int idx = j * 256 + t;
                if (j < 4 || idx < 1072) {
                    const float4 v = sc4[idx];
                    const float e4[4] = {v.x, v.y, v.z, v.w};
#pragma unroll
                    for (int e = 0; e < 4; ++e) {
                        const int ee  = 4 * idx + e;
                        const int row = ee / 67;        // compiler magic-div
                        const int d   = ee - row * 67;
                        lact[row * ASTR + 64 + d] = f2bf(e4[e]);
                    }
                }
            }
        }
        // ---- zero tail ----
        if (t < 64) lact[t * ASTR + 131] = 0;
        for (int i = t; i < 64 * 14; i += 256) {
            const int row = i / 14, j2 = i - row * 14;
            ldsd[row * 84 + 66 + j2] = 0;
        }
        __syncthreads();

        // A-frags: one aligned b128 per kstep
        const unsigned short* arow = lact + (w * 16 + m) * ASTR;
        s16x8 af[5];
#pragma unroll
        for (int s = 0; s < 5; ++s)
            af[s] = *(const s16x8*)(arow + s * 32 + q * 8);

        const s16x8* bfr = (const s16x8*)ldsb;

        f32x4 acc[8];
#pragma unroll
        for (int nt = 0; nt < 8; ++nt) acc[nt] = (f32x4){0.f, 0.f, 0.f, 0.f};

#pragma unroll
        for (int s = 0; s < 2; ++s)                  // full tiles: all 8 ntiles
#pragma unroll
            for (int nt = 0; nt < 8; ++nt)
                acc[nt] = __builtin_amdgcn_mfma_f32_16x16x32_bf16(
                    bfr[(s * 8 + nt) * 64 + l], af[s], acc[nt], 0, 0, 0);
#pragma unroll
        for (int s = 2; s < 5; ++s)                  // proj-only: ntiles 0..3
#pragma unroll
            for (int nt = 0; nt < 4; ++nt)
                acc[nt] = __builtin_amdgcn_mfma_f32_16x16x32_bf16(
                    bfr[(16 + (s - 2) * 4 + nt) * 64 + l], af[s], acc[nt], 0, 0, 0);

        // Epilogue: lane holds data-row (l&15); channels nt*16 + q*4 + reg.
        const int row_g = row0 + w * 16 + m;
        unsigned short* rowp = cmb + (size_t)row_g * NCH;
        const int chq = q * 4;
#pragma unroll
        for (int nt = 0; nt < 8; ++nt) {
            f32x4 a = acc[nt];
            if (nt < 4) {
                const float4 bv = *(const float4*)(bias + nt * 16 + chq);
                a[0] += bv.x; a[1] += bv.y; a[2] += bv.z; a[3] += bv.w;
            }
            *(uint2*)(rowp + nt * 16 + chq) =
                make_uint2(pack2(a[0], a[1]), pack2(a[2], a[3]));
        }
        __syncthreads();   // act buffer reused next iteration
    }

    // ================== per-slab producer/consumer barrier =================
    __threadfence();                       // device-scope release of cmb writes
    __syncthreads();
    if (t == 0) {
        __hip_atomic_fetch_add(&bar[g * 16], 1u, __ATOMIC_RELEASE,
                               __HIP_MEMORY_SCOPE_AGENT);
        while (__hip_atomic_load(&bar[g * 16], __ATOMIC_ACQUIRE,
                                 __HIP_MEMORY_SCOPE_AGENT) < 64u)
            __builtin_amdgcn_s_sleep(2);
    }
    __syncthreads();

    // ========================== gather phase ===============================
    // 16 groups per block, 4 per wave; slab g -> groups g*1024 + bs*16 + ...
    const int h  = l >> 5;
    const int ln = l & 31;
    const float NEG = -__builtin_inff();

#pragma unroll 1
    for (int gi = 0; gi < 4; ++gi) {
        const int grp   = g * 1024 + bs * 16 + w * 4 + gi;
        const int pairA = grp * 2;
        const int b     = grp >> 9;              // 512 groups per batch

        const int* iA = indexes + (size_t)pairA * K_;   // uniform -> s_load
        const int* iB = iA + K_;
        const char* cb = (const char*)cmb + (size_t)b * N_ * 256;

        float m0 = NEG, m1 = NEG;
#pragma unroll
        for (int k = 0; k < K_; ++k) {
            const int ia = iA[k], ib = iB[k];
            const int ik = h ? ib : ia;
            const int iku = ik < 0 ? 0 : ik;
            const unsigned int v =
                *(const unsigned int*)(cb + ((size_t)iku << 8) + ln * 4);
            const bool inv = ik < 0;
            m0 = fmaxf(m0, inv ? NEG : bf2f((unsigned short)(v & 0xffff)));
            m1 = fmaxf(m1, inv ? NEG : bf2f((unsigned short)(v >> 16)));
        }
        if (ux) {
            const int i0 = h ? iB[0] : iA[0];    // center, always valid
            const unsigned int c =
                *(const unsigned int*)(cb + ((size_t)i0 << 8) + 128 + ln * 4);
            m0 -= bf2f((unsigned short)(c & 0xffff));
            m1 -= bf2f((unsigned short)(c >> 16));
        }
        const int pair = pairA + h;
        *(float2*)(out + (size_t)pair * 64 + ln * 2) = make_float2(m0, m1);
    }
}

// ---------------------------------------------------------------------------
// Fallback (ws too small): fully fused, recomputes projections per gather.
// ---------------------------------------------------------------------------
__global__ __launch_bounds__(256, 1) void fused_fallback_kernel(
    const float* __restrict__ x, const float* __restrict__ xcm,
    const int* __restrict__ indexes,
    const float* __restrict__ w1, const float* __restrict__ w2,
    const float* __restrict__ bias, const int* __restrict__ use_x_p,
    float* __restrict__ out)
{
    const int lane = threadIdx.x & 63;
    const int pair = (blockIdx.x * blockDim.x + threadIdx.x) >> 6;
    const int b    = pair >> 10;
    const int ux   = use_x_p[0];

    float W1[DINC_];
#pragma unroll
    for (int j = 0; j < DINC_; ++j) W1[j] = w1[lane * DINC_ + j];
    float W2[DIN_];
#pragma unroll
    for (int j = 0; j < DIN_; ++j) W2[j] = w2[lane * DIN_ + j];
    const float bv = bias[lane];

    const int* idxp  = indexes + (size_t)pair * K_;
    const int  myidx = idxp[lane & 31];

    const float NEG = -__builtin_inff();
    float m = NEG;
    for (int k = 0; k < K_; ++k) {
        const int ik = __shfl(myidx, k, 64);
        if (ik < 0) continue;
        const float* xc_row = xcm + ((size_t)b * N_ + ik) * DINC_;
        float a1 = bv;
#pragma unroll
        for (int j = 0; j < DINC_; ++j) a1 += xc_row[j] * W1[j];
        if (ux) {
            const float* x_row = x + ((size_t)b * N_ + ik) * DIN_;
            float a2 = 0.f;
#pragma unroll
            for (int j = 0; j < DIN_; ++j) a2 += x_row[j] * W2[j];
            a1 += a2;
        }
        m = fmaxf(m, a1);
    }
    if (ux) {
        const int i0 = __shfl(myidx, 0, 64);
        const float* x_row = x + ((size_t)b * N_ + i0) * DIN_;
        float a2 = 0.f;
#pragma unroll
        for (int j = 0; j < DIN_; ++j) a2 += x_row[j] * W2[j];
        m -= a2;
    }
    out[(size_t)pair * DOUT_ + lane] = m;
}

extern "C" void kernel_launch(void* const* d_in, const int* in_sizes, int n_in,
                              void* d_out, int out_size, void* d_ws, size_t ws_size,
                              hipStream_t stream)
{
    const float* x    = (const float*)d_in[0];
    const float* xcm  = (const float*)d_in[1];
    const int*   idx  = (const int*)d_in[2];
    const float* w1   = (const float*)d_in[3];
    const float* w2   = (const float*)d_in[4];
    const float* bias = (const float*)d_in[5];
    const int*   ux   = (const int*)d_in[6];
    float* out = (float*)d_out;

    const size_t cmb_bytes = (size_t)ROWS_ * NCH * sizeof(unsigned short); // 16 MiB
    const size_t wf_bytes  = (size_t)NFRAG * 16;                           // 28 KB
    const size_t bar_bytes = 128 * sizeof(unsigned int);                   // 512 B
    const int npairs = B_ * S_;   // 16384

    if (ws_size >= cmb_bytes + wf_bytes + bar_bytes) {
        unsigned short* cmb = (unsigned short*)d_ws;
        uint4* wf = (uint4*)((char*)d_ws + cmb_bytes);
        unsigned int* bar = (unsigned int*)((char*)d_ws + cmb_bytes + wf_bytes);

        // 8 blocks: 1792 frag threads + 128 barrier-zero threads (+ slack)
        prep_kernel<<<8, 256, 0, stream>>>(w1, w2, ux, wf, bar);
        fused_kernel<<<NBLK, 256, 0, stream>>>(x, xcm, wf, bias, idx, ux,
                                               cmb, bar, out);
    } else {
        fused_fallback_kernel<<<npairs / 4, 256, 0, stream>>>(x, xcm, idx, w1, w2,
                                                              bias, ux, out);
    }
}

// Round 11
// 106.216 us; speedup vs baseline: 1.8016x; 1.8016x over previous
//
#include <hip/hip_runtime.h>

#define B_    16
#define N_    4096
#define S_    1024
#define K_    32
#define DIN_  64
#define DINC_ 67
#define DOUT_ 64
#define ROWS_ (B_ * N_)
#define NCH   128            // 64 proj + 64 xp output columns
#define NTILE 28             // nonzero weight tiles (s0:8, s1:8, s2:4, s3:4, s4:4)
#define NFRAG (NTILE * 64)   // 1792 16B-chunks = 28 KB
#define ASTR  168            // LDS act row stride in ushorts (336 B = 21*16)
#define WLDSB (NTILE * 64 * 16)        // 28672 B weight frags
#define ALDSB (64 * ASTR * 2)          // 21504 B activations
// K-REORDER: k' = 0..63 -> x (w2), k' = 64..130 -> xc (w1), 131..159 zero.
// cmb row: 128 bf16 = [proj x64 | xp x64] = 256 B

typedef float f32x4 __attribute__((ext_vector_type(4)));
typedef short s16x8 __attribute__((ext_vector_type(8)));

static __device__ __forceinline__ unsigned short f2bf(float f) {
    unsigned int u = __float_as_uint(f);
    u = (u + 0x7fffu + ((u >> 16) & 1u)) >> 16;   // RNE
    return (unsigned short)u;
}
static __device__ __forceinline__ float bf2f(unsigned short h) {
    return __uint_as_float((unsigned int)h << 16);
}
static __device__ __forceinline__ unsigned int pack2(float a, float b) {
    return (unsigned int)f2bf(a) | ((unsigned int)f2bf(b) << 16);
}
// bf16 pair (packed in a dword) -> two f32 via pure bit ops
static __device__ __forceinline__ float bflo(unsigned int d) {
    return __uint_as_float(d << 16);
}
static __device__ __forceinline__ float bfhi(unsigned int d) {
    return __uint_as_float(d & 0xffff0000u);
}

// ---------------------------------------------------------------------------
// Prep: build the 28 nonzero MFMA weight-fragment tiles (identical to r9).
// ---------------------------------------------------------------------------
__global__ __launch_bounds__(256) void prep_kernel(
    const float* __restrict__ w1, const float* __restrict__ w2,
    const int* __restrict__ use_x_p, uint4* __restrict__ wf)
{
    const int id = blockIdx.x * 256 + threadIdx.x;
    if (id >= NFRAG) return;
    const int tile = id >> 6;
    const int l    = id & 63;
    const int s    = (tile < 16) ? (tile >> 3) : (2 + ((tile - 16) >> 2));
    const int nt   = (tile < 16) ? (tile & 7)  : ((tile - 16) & 3);
    const int q    = l >> 4, m = l & 15;
    const int c    = nt * 16 + m;
    const int ux   = use_x_p[0];

    unsigned int w[4];
#pragma unroll
    for (int p = 0; p < 4; ++p) {
        unsigned short h[2];
#pragma unroll
        for (int e = 0; e < 2; ++e) {
            const int k = s * 32 + q * 8 + p * 2 + e;   // k'
            float v = 0.f;
            if (c < 64) {
                if (k < 64)         v = ux ? w2[c * DIN_ + k] : 0.f;
                else if (k < 131)   v = w1[c * DINC_ + (k - 64)];
            } else {
                if (k < 64)         v = w2[(c - 64) * DIN_ + k];
            }
            h[e] = f2bf(v);
        }
        w[p] = (unsigned int)h[0] | ((unsigned int)h[1] << 16);
    }
    wf[id] = make_uint4(w[0], w[1], w[2], w[3]);
}

// ---------------------------------------------------------------------------
// Kernel 1: projection via MFMA 16x16x32 bf16 — identical to the r9 kernel
// (best measured). wf via global_load_lds w=16; x float4; xc flat float4
// stream; 28 MFMA; packed bf16 epilogue.
// ---------------------------------------------------------------------------
__global__ __launch_bounds__(256) void proj_kernel(
    const float* __restrict__ x, const float* __restrict__ xcm,
    const uint4* __restrict__ wf, const float* __restrict__ bias,
    unsigned short* __restrict__ cmb)
{
    __shared__ char smem[WLDSB + ALDSB];      // 50176 B -> 3 blocks/CU
    uint4* ldsb          = (uint4*)smem;
    unsigned short* lact = (unsigned short*)(smem + WLDSB);
    unsigned int*  ldsd  = (unsigned int*)lact;

    const int t    = threadIdx.x;
    // XCD swizzle: xcd g computes batches 2g,2g+1 (matches gather's reader slab)
    const int row0 = (blockIdx.x & 7) * (ROWS_ / 8) + (blockIdx.x >> 3) * 64;

#pragma unroll
    for (int j = 0; j < 7; ++j) {
        const int idx = j * 256 + t;
        __builtin_amdgcn_global_load_lds(
            (const __attribute__((address_space(1))) void*)(wf + idx),
            (__attribute__((address_space(3))) void*)(ldsb + idx), 16, 0, 0);
    }

    {
        const float4* sx4 = (const float4*)(x + (size_t)row0 * DIN_);
#pragma unroll
        for (int j = 0; j < 4; ++j) {
            const int idx = j * 256 + t;           // 0..1023
            const float4 v = sx4[idx];
            const int row = idx >> 4, f4 = idx & 15;
            *(uint2*)(ldsd + row * 84 + f4 * 2) =
                make_uint2(pack2(v.x, v.y), pack2(v.z, v.w));
        }
    }
    {
        const float4* sc4 = (const float4*)(xcm + (size_t)row0 * DINC_);
#pragma unroll
        for (int j = 0; j < 5; ++j) {
            const int idx = j * 256 + t;
            if (j < 4 || idx < 1072) {
                const float4 v = sc4[idx];
                const float e4[4] = {v.x, v.y, v.z, v.w};
#pragma unroll
                for (int e = 0; e < 4; ++e) {
                    const int ee  = 4 * idx + e;
                    const int row = ee / 67;        // compiler magic-div
                    const int d   = ee - row * 67;
                    lact[row * ASTR + 64 + d] = f2bf(e4[e]);
                }
            }
        }
    }
    if (t < 64) lact[t * ASTR + 131] = 0;
    for (int i = t; i < 64 * 14; i += 256) {
        const int row = i / 14, j2 = i - row * 14;
        ldsd[row * 84 + 66 + j2] = 0;
    }
    __syncthreads();

    const int l = t & 63;
    const int w = __builtin_amdgcn_readfirstlane(t >> 6);
    const int q = l >> 4, m = l & 15;

    const unsigned short* arow = lact + (w * 16 + m) * ASTR;
    s16x8 af[5];
#pragma unroll
    for (int s = 0; s < 5; ++s)
        af[s] = *(const s16x8*)(arow + s * 32 + q * 8);

    const s16x8* bfr = (const s16x8*)ldsb;

    f32x4 acc[8];
#pragma unroll
    for (int nt = 0; nt < 8; ++nt) acc[nt] = (f32x4){0.f, 0.f, 0.f, 0.f};

#pragma unroll
    for (int s = 0; s < 2; ++s)                  // full tiles: all 8 ntiles
#pragma unroll
        for (int nt = 0; nt < 8; ++nt)
            acc[nt] = __builtin_amdgcn_mfma_f32_16x16x32_bf16(
                bfr[(s * 8 + nt) * 64 + l], af[s], acc[nt], 0, 0, 0);
#pragma unroll
    for (int s = 2; s < 5; ++s)                  // proj-only tiles: ntiles 0..3
#pragma unroll
        for (int nt = 0; nt < 4; ++nt)
            acc[nt] = __builtin_amdgcn_mfma_f32_16x16x32_bf16(
                bfr[(16 + (s - 2) * 4 + nt) * 64 + l], af[s], acc[nt], 0, 0, 0);

    const int row_g = row0 + w * 16 + m;
    unsigned short* rowp = cmb + (size_t)row_g * NCH;
    const int chq = q * 4;
#pragma unroll
    for (int nt = 0; nt < 8; ++nt) {
        f32x4 a = acc[nt];
        if (nt < 4) {
            const float4 bv = *(const float4*)(bias + nt * 16 + chq);
            a[0] += bv.x; a[1] += bv.y; a[2] += bv.z; a[3] += bv.w;
        }
        *(uint2*)(rowp + nt * 16 + chq) =
            make_uint2(pack2(a[0], a[1]), pack2(a[2], a[3]));
    }
}

// ---------------------------------------------------------------------------
// Kernel 2 (round-11): gather + masked max, 4 pairs per wave.
// lane = (p, ln): p = lane>>4 picks the pair, ln = lane&15 reads 8 B =
// channels 4ln..4ln+3 of the proj half-row. One dwordx2 per lane per k
// covers 4 half-rows (512 B/instr). Invalid k uses the DUPLICATE-MEMBER
// trick: replace idx<0 with the center index idx[p][0] (always valid and
// always in the max set) -> zero per-element masking. bf16->f32 via shl/and.
// XCD slab swizzle unchanged.
// ---------------------------------------------------------------------------
__global__ __launch_bounds__(256) void gather_max_kernel(
    const int* __restrict__ indexes, const unsigned short* __restrict__ cmb,
    const int* __restrict__ use_x_p, float* __restrict__ out)
{
    const int lane = threadIdx.x & 63;
    const int p    = lane >> 4;
    const int ln   = lane & 15;
    const int wv   = __builtin_amdgcn_readfirstlane(threadIdx.x >> 6);
    // slab g = blockIdx&7 -> pairs g*2048 .. +2048; 128 blocks/slab, 16 pairs/blk
    const int pair0 = (blockIdx.x & 7) * 2048 + (blockIdx.x >> 3) * 16 + wv * 4;
    const int b     = pair0 >> 10;       // 4 consecutive pairs: same batch
    const int ux    = use_x_p[0];

    const int* i0 = indexes + (size_t)(pair0 + 0) * K_;   // uniform -> s_load
    const int* i1 = i0 + K_;
    const int* i2 = i1 + K_;
    const int* i3 = i2 + K_;
    const char* cb = (const char*)cmb + (size_t)b * N_ * 256;

    const int c0 = i0[0], c1 = i1[0], c2 = i2[0], c3 = i3[0]; // centers (valid)
    const float NEG = -__builtin_inff();
    float m0 = NEG, m1 = NEG, m2 = NEG, m3 = NEG;

#pragma unroll
    for (int k = 0; k < K_; ++k) {
        int r0 = i0[k], r1 = i1[k], r2 = i2[k], r3 = i3[k];   // scalar
        r0 = r0 < 0 ? c0 : r0;                                // s_cselect:
        r1 = r1 < 0 ? c1 : r1;                                // dup-member trick
        r2 = r2 < 0 ? c2 : r2;
        r3 = r3 < 0 ? c3 : r3;
        const int rp = p == 0 ? r0 : p == 1 ? r1 : p == 2 ? r2 : r3;
        const uint2 d = *(const uint2*)(cb + ((size_t)rp << 8) + ln * 8);
        m0 = fmaxf(m0, bflo(d.x));
        m1 = fmaxf(m1, bfhi(d.x));
        m2 = fmaxf(m2, bflo(d.y));
        m3 = fmaxf(m3, bfhi(d.y));
    }
    if (ux) {
        const int cp = p == 0 ? c0 : p == 1 ? c1 : p == 2 ? c2 : c3;
        const uint2 c = *(const uint2*)(cb + ((size_t)cp << 8) + 128 + ln * 8);
        m0 -= bflo(c.x);
        m1 -= bfhi(c.x);
        m2 -= bflo(c.y);
        m3 -= bfhi(c.y);
    }
    *(float4*)(out + (size_t)(pair0 + p) * 64 + ln * 4) =
        make_float4(m0, m1, m2, m3);
}

// ---------------------------------------------------------------------------
// Fallback (ws too small): fully fused, recomputes projections per gather.
// ---------------------------------------------------------------------------
__global__ __launch_bounds__(256, 1) void fused_fallback_kernel(
    const float* __restrict__ x, const float* __restrict__ xcm,
    const int* __restrict__ indexes,
    const float* __restrict__ w1, const float* __restrict__ w2,
    const float* __restrict__ bias, const int* __restrict__ use_x_p,
    float* __restrict__ out)
{
    const int lane = threadIdx.x & 63;
    const int pair = (blockIdx.x * blockDim.x + threadIdx.x) >> 6;
    const int b    = pair >> 10;
    const int ux   = use_x_p[0];

    float W1[DINC_];
#pragma unroll
    for (int j = 0; j < DINC_; ++j) W1[j] = w1[lane * DINC_ + j];
    float W2[DIN_];
#pragma unroll
    for (int j = 0; j < DIN_; ++j) W2[j] = w2[lane * DIN_ + j];
    const float bv = bias[lane];

    const int* idxp  = indexes + (size_t)pair * K_;
    const int  myidx = idxp[lane & 31];

    const float NEG = -__builtin_inff();
    float m = NEG;
    for (int k = 0; k < K_; ++k) {
        const int ik = __shfl(myidx, k, 64);
        if (ik < 0) continue;
        const float* xc_row = xcm + ((size_t)b * N_ + ik) * DINC_;
        float a1 = bv;
#pragma unroll
        for (int j = 0; j < DINC_; ++j) a1 += xc_row[j] * W1[j];
        if (ux) {
            const float* x_row = x + ((size_t)b * N_ + ik) * DIN_;
            float a2 = 0.f;
#pragma unroll
            for (int j = 0; j < DIN_; ++j) a2 += x_row[j] * W2[j];
            a1 += a2;
        }
        m = fmaxf(m, a1);
    }
    if (ux) {
        const int i0 = __shfl(myidx, 0, 64);
        const float* x_row = x + ((size_t)b * N_ + i0) * DIN_;
        float a2 = 0.f;
#pragma unroll
        for (int j = 0; j < DIN_; ++j) a2 += x_row[j] * W2[j];
        m -= a2;
    }
    out[(size_t)pair * DOUT_ + lane] = m;
}

extern "C" void kernel_launch(void* const* d_in, const int* in_sizes, int n_in,
                              void* d_out, int out_size, void* d_ws, size_t ws_size,
                              hipStream_t stream)
{
    const float* x    = (const float*)d_in[0];
    const float* xcm  = (const float*)d_in[1];
    const int*   idx  = (const int*)d_in[2];
    const float* w1   = (const float*)d_in[3];
    const float* w2   = (const float*)d_in[4];
    const float* bias = (const float*)d_in[5];
    const int*   ux   = (const int*)d_in[6];
    float* out = (float*)d_out;

    const size_t cmb_bytes = (size_t)ROWS_ * NCH * sizeof(unsigned short); // 16 MiB
    const size_t wf_bytes  = (size_t)NFRAG * 16;                           // 28 KB
    const int npairs = B_ * S_;   // 16384

    if (ws_size >= cmb_bytes + wf_bytes) {
        unsigned short* cmb = (unsigned short*)d_ws;
        uint4* wf = (uint4*)((char*)d_ws + cmb_bytes);

        prep_kernel<<<(NFRAG + 255) / 256, 256, 0, stream>>>(w1, w2, ux, wf);
        proj_kernel<<<ROWS_ / 64, 256, 0, stream>>>(x, xcm, wf, bias, cmb);
        // 16384 pairs / (4 pairs/wave * 4 waves/block) = 1024 blocks
        gather_max_kernel<<<npairs / 16, 256, 0, stream>>>(idx, cmb, ux, out);
    } else {
        fused_fallback_kernel<<<npairs / 4, 256, 0, stream>>>(x, xcm, idx, w1, w2,
                                                              bias, ux, out);
    }
}